// Round 13
// baseline (342.934 us; speedup 1.0000x reference)
//
#include <hip/hip_runtime.h>
#include <hip/hip_bf16.h>

#define NN 50000
#define NE 800000
#define NG 64
#define C1 128    // H1*D1
#define D2 32
#define NB 196    // (NN+255)/256 scan blocks
#define BN_EPS 1e-5f

// ---- constant-block layout (float offsets inside cst) ----
#define CST_A   0      // [2]  el coeff per head (rank-1 collapse of layer-1 projection)
#define CST_B   2      // [2]  er coeff per head
#define CST_P   4      // [128] W1 * bn1_scale
#define CST_Q   132    // [128] res1 * bn1_scale
#define CST_R   260    // [128] (b1-mean)*scale+beta
#define CST_SC2 388    // [32]  bn2 scale
#define CST_RC2 420    // [32]  (b2-mean2)*scale2+beta2
#define CST_SD  452    // [128] bnD scale
#define CST_RD  580    // [128] (bd1-meanD)*scaleD+betaD
#define CST_N   1024

// ---- workspace layout (4-byte-unit offsets inside d_ws), total ~14.0 MiB ----
#define UO_DEG   0                        // int[NN]   (zeroed)
#define UO_CUR   50000                    // int[NN]   (zeroed)
#define ZERO_UNITS 100000                 // only deg+cur need zeroing
#define UO_FLAG  100000                   // int[1]
#define UO_LOC   100004                   // int[NN]   block-local exclusive scan
#define UO_BSUM  150004                   // int[256]  per-block sums
#define UO_CARRY 150260                   // int[256]  exclusive scan of bsum
#define UO_ESRC  150516                   // int[NE]
#define UO_FCAN  950516                   // float[NN] canonical fp32 feat
#define UO_CST   1000516                  // float[CST_N]
#define UO_F2    1001544                  // ushort[D2*NN] bf16-packed (16B aligned)
#define UO_RS2   1801544                  // float[D2*NN] resid2; overwritten with h2 by k_final
#define UO_EL2   3401544                  // float[NN]
#define UO_ER2   3451544                  // float[NN]
#define UO_END   3501544                  // ~14.0 MB

__device__ __forceinline__ float lrelu(float x) { return x > 0.0f ? x : 0.2f * x; }
// raw bf16 <-> fp32 (RNE), self-contained
__device__ __forceinline__ float bu2f(unsigned int u) {
    union { unsigned int i; float f; } v; v.i = (u & 0xFFFFu) << 16; return v.f;
}
__device__ __forceinline__ unsigned short f2bu(float f) {
    union { float f; unsigned int i; } v; v.f = f;
    unsigned int r = v.i + 0x7FFFu + ((v.i >> 16) & 1u);
    return (unsigned short)(r >> 16);
}
// packed bf16-pair unpack: lo = first value, hi = second value (1 VALU op each)
__device__ __forceinline__ float pk_lo(unsigned int w) {
    union { unsigned int i; float f; } v; v.i = w << 16; return v.f;
}
__device__ __forceinline__ float pk_hi(unsigned int w) {
    union { unsigned int i; float f; } v; v.i = w & 0xFFFF0000u; return v.f;
}
// dtype-aware weight load: bf=0 -> fp32 array, bf=1 -> bf16 array
__device__ __forceinline__ float ldw(const void* p, int i, int bf) {
    return bf ? bu2f(((const unsigned short*)p)[i]) : ((const float*)p)[i];
}
// reconstruct CSR offset from two-level scan (no phase-C scatter kernel)
__device__ __forceinline__ int offat(const int* loc, const int* carry, int i) {
    return loc[i] + carry[i >> 8];
}
// 64-lane sniff of feat's first 256 words; returns 1 if bf16-packed
__device__ __forceinline__ int sniff64(const unsigned int* fw, int l) {
    int cnt = 0;
    for (int j = l; j < 256; j += 64) {
        unsigned int b = (fw[j] >> 8) & 0x7Fu;   // byte1: fp32 mantissa vs bf16 sign|exp[7:1]
        cnt += (b >= 0x3Au && b <= 0x41u) ? 1 : 0;
    }
#pragma unroll
    for (int m = 32; m >= 1; m >>= 1) cnt += __shfl_xor(cnt, m);
    return (cnt > 128) ? 1 : 0;
}

// ---------------- canonicalize feat to fp32 + degree histogram (self-sniffing) ----------------
__global__ void k_prep(const void* __restrict__ feat, const int* __restrict__ dst,
                       float* __restrict__ fcan, int* __restrict__ deg) {
    __shared__ int sBf;
    int t = threadIdx.x;
    if (t < 64) {
        int bf = sniff64((const unsigned int*)feat, t);
        if (t == 0) sBf = bf;
    }
    __syncthreads();
    int bf = sBf;
    int k = blockIdx.x * blockDim.x + t;
    if (k < NN) fcan[k] = ldw(feat, k, bf);
    if (k < NE) atomicAdd(&deg[dst[k]], 1);
}

// ---------------- fold all the tiny weights into fp32 constants (self-sniffing) ----------------
__global__ void k_const(const void* feat,
                        const void* W1, const void* al1, const void* ar1,
                        const void* res1, const void* b1,
                        const void* g1g, const void* g1b, const void* g1m, const void* g1v,
                        const void* b2v, const void* g2g, const void* g2b,
                        const void* g2m, const void* g2v,
                        const void* bd1, const void* gdg, const void* gdb,
                        const void* gdm, const void* gdv,
                        int* __restrict__ flag, float* cst) {
    __shared__ int sBf;
    int t = threadIdx.x;  // 128 threads
    if (t < 64) {
        int b = sniff64((const unsigned int*)feat, t);
        if (t == 0) { sBf = b; *flag = b; }
    }
    __syncthreads();
    int bf = sBf;
    if (t < 2) {
        float a = 0.0f, b = 0.0f;
        for (int d = 0; d < 64; ++d) {
            float w = ldw(W1, t * 64 + d, bf);
            a += w * ldw(al1, t * 64 + d, bf);
            b += w * ldw(ar1, t * 64 + d, bf);
        }
        cst[CST_A + t] = a;
        cst[CST_B + t] = b;
    }
    {   // layer-1 BN fold: h1 = relu(p*T + q*x + r)
        float sc = rsqrtf(ldw(g1v, t, bf) + BN_EPS) * ldw(g1g, t, bf);
        cst[CST_P + t] = ldw(W1, t, bf) * sc;
        cst[CST_Q + t] = ldw(res1, t, bf) * sc;
        cst[CST_R + t] = (ldw(b1, t, bf) - ldw(g1m, t, bf)) * sc + ldw(g1b, t, bf);
    }
    if (t < D2) {
        float sc = rsqrtf(ldw(g2v, t, bf) + BN_EPS) * ldw(g2g, t, bf);
        cst[CST_SC2 + t] = sc;
        cst[CST_RC2 + t] = (ldw(b2v, t, bf) - ldw(g2m, t, bf)) * sc + ldw(g2b, t, bf);
    }
    {   // decoder BN fold (includes bd1)
        float sc = rsqrtf(ldw(gdv, t, bf) + BN_EPS) * ldw(gdg, t, bf);
        cst[CST_SD + t] = sc;
        cst[CST_RD + t] = (ldw(bd1, t, bf) - ldw(gdm, t, bf)) * sc + ldw(gdb, t, bf);
    }
}

// ---------------- scan phase A ----------------
__global__ __launch_bounds__(256) void k_scanA(const int* __restrict__ deg,
                                               int* __restrict__ loc,
                                               int* __restrict__ bsum) {
    __shared__ int tmp[256];
    int t = threadIdx.x;
    int i = blockIdx.x * 256 + t;
    int v = (i < NN) ? deg[i] : 0;
    tmp[t] = v;
    __syncthreads();
    for (int off = 1; off < 256; off <<= 1) {
        int u = (t >= off) ? tmp[t - off] : 0;
        __syncthreads();
        tmp[t] += u;
        __syncthreads();
    }
    if (i < NN) loc[i] = tmp[t] - v;
    if (t == 255) bsum[blockIdx.x] = tmp[255];
}

// ---------------- scan phase B ----------------
__global__ __launch_bounds__(256) void k_scanB(const int* __restrict__ bsum,
                                               int* __restrict__ carry) {
    __shared__ int tmp[256];
    int t = threadIdx.x;
    int v = (t < NB) ? bsum[t] : 0;
    tmp[t] = v;
    __syncthreads();
    for (int off = 1; off < 256; off <<= 1) {
        int u = (t >= off) ? tmp[t - off] : 0;
        __syncthreads();
        tmp[t] += u;
        __syncthreads();
    }
    carry[t] = tmp[t] - v;
}

// ---------------- CSR fill ----------------
__global__ void k_fill(const int* __restrict__ src, const int* __restrict__ dst,
                       const int* __restrict__ loc, const int* __restrict__ carry,
                       int* __restrict__ cur, int* __restrict__ esrc) {
    int k = blockIdx.x * blockDim.x + threadIdx.x;
    if (k >= NE) return;
    int d = dst[k];
    int pos = offat(loc, carry, d) + atomicAdd(&cur[d], 1);
    esrc[pos] = src[k];
}

// ---------------- layer-1: 32 nodes/block; bf16 (c,c+64)-packed LDS projection ----------------
// LDS-instruction-bound fix: weights/h1 stored as bf16 pairs (channel c with c+64 in one
// 32-bit word), weights transposed [l][cw] so a lane reads uint2 = 4 c-values/instruction.
__global__ __launch_bounds__(256) void k_layer1(
        const float* __restrict__ fcan, const void* W2, const void* res2,
        const void* al2, const void* ar2,
        const int* __restrict__ flag, const float* __restrict__ cst,
        const int* __restrict__ loc, const int* __restrict__ carry,
        const int* __restrict__ esrc,
        unsigned short* __restrict__ F2, float* __restrict__ RS2,
        float* __restrict__ EL2, float* __restrict__ ER2) {
    __shared__ unsigned int sW2pk[32 * 66];  // [l][cw] pad 66: 2-way bank alias = free
    __shared__ unsigned int sR2pk[32 * 66];
    __shared__ unsigned int sH1pk[32 * 66];  // [slot][cw]: writes conflict-free, reads broadcast
    __shared__ float sP[C1], sQ[C1], sR[C1];
    __shared__ float sAl[D2], sAr[D2];
    int t = threadIdx.x;
    int bf = *flag;
    for (int u = t; u < 32 * 64; u += 256) {
        int l2 = u >> 6, cw = u & 63;
        unsigned int wlo = (unsigned int)f2bu(ldw(W2, cw * D2 + l2, bf));
        unsigned int whi = (unsigned int)f2bu(ldw(W2, (cw + 64) * D2 + l2, bf));
        sW2pk[l2 * 66 + cw] = wlo | (whi << 16);
        unsigned int rlo = (unsigned int)f2bu(ldw(res2, cw * D2 + l2, bf));
        unsigned int rhi = (unsigned int)f2bu(ldw(res2, (cw + 64) * D2 + l2, bf));
        sR2pk[l2 * 66 + cw] = rlo | (rhi << 16);
    }
    if (t < C1) { sP[t] = cst[CST_P + t]; sQ[t] = cst[CST_Q + t]; sR[t] = cst[CST_R + t]; }
    if (t < D2) { sAl[t] = ldw(al2, t, bf); sAr[t] = ldw(ar2, t, bf); }
    __syncthreads();

    int l = t & 31;
    int g = t >> 5;              // 8 groups of 32 lanes
    int base = blockIdx.x * 32;
    float A0 = cst[CST_A + 0], A1 = cst[CST_A + 1];
    float B0 = cst[CST_B + 0], B1 = cst[CST_B + 1];

    // --- phase 1: each group gathers 4 nodes sequentially (group-uniform control flow)
    for (int k = 0; k < 4; ++k) {
        int slot = g * 4 + k;
        int i = base + slot;
        if (i >= NN) break;
        float fi = fcan[i];
        int e0 = offat(loc, carry, i);
        int e1 = (i + 1 < NN) ? offat(loc, carry, i + 1) : NE;
        float S0 = 0.0f, S1 = 0.0f, N0 = 0.0f, N1 = 0.0f;
        for (int e = e0 + l; e < e1; e += 32) {
            int s = esrc[e];
            float fs = fcan[s];
            float w0 = __expf(lrelu(A0 * fs + B0 * fi));
            float w1 = __expf(lrelu(A1 * fs + B1 * fi));
            S0 += w0; N0 += w0 * fs;
            S1 += w1; N1 += w1 * fs;
        }
#pragma unroll
        for (int m = 16; m >= 1; m >>= 1) {
            S0 += __shfl_xor(S0, m); N0 += __shfl_xor(N0, m);
            S1 += __shfl_xor(S1, m); N1 += __shfl_xor(N1, m);
        }
        float T0 = S0 > 0.0f ? N0 / S0 : 0.0f;
        float T1 = S1 > 0.0f ? N1 / S1 : 0.0f;
        // h1 at c = l, l+32, l+64, l+96; pack (c, c+64) pairs
        float h0  = fmaxf(sP[l]      * T0 + sQ[l]      * fi + sR[l],      0.0f);
        float h1v = fmaxf(sP[l + 32] * T0 + sQ[l + 32] * fi + sR[l + 32], 0.0f);
        float h2v = fmaxf(sP[l + 64] * T1 + sQ[l + 64] * fi + sR[l + 64], 0.0f);
        float h3v = fmaxf(sP[l + 96] * T1 + sQ[l + 96] * fi + sR[l + 96], 0.0f);
        sH1pk[slot * 66 + l]      = (unsigned int)f2bu(h0)  | ((unsigned int)f2bu(h2v) << 16);
        sH1pk[slot * 66 + l + 32] = (unsigned int)f2bu(h1v) | ((unsigned int)f2bu(h3v) << 16);
    }
    __syncthreads();

    // --- phase 2: wave owns 8 nodes; half-wave lane keeps 4 nodes in registers;
    //     uint2 reads deliver 4 channels (cw, cw+1, +64 partners) per instruction
    int w = t >> 6;
    int half = (t >> 5) & 1;
    int nb0 = w * 8 + half * 4;
    float aF[4] = {0.f, 0.f, 0.f, 0.f}, aR[4] = {0.f, 0.f, 0.f, 0.f};
    for (int cw = 0; cw < 64; cw += 2) {
        uint2 wq = *(const uint2*)&sW2pk[l * 66 + cw];
        uint2 rq = *(const uint2*)&sR2pk[l * 66 + cw];
        float w_a = pk_lo(wq.x), w_b = pk_hi(wq.x), w_c = pk_lo(wq.y), w_d = pk_hi(wq.y);
        float r_a = pk_lo(rq.x), r_b = pk_hi(rq.x), r_c = pk_lo(rq.y), r_d = pk_hi(rq.y);
#pragma unroll
        for (int n = 0; n < 4; ++n) {
            uint2 hq = *(const uint2*)&sH1pk[(nb0 + n) * 66 + cw];   // broadcast
            float h_a = pk_lo(hq.x), h_b = pk_hi(hq.x), h_c = pk_lo(hq.y), h_d = pk_hi(hq.y);
            aF[n] = fmaf(h_a, w_a, fmaf(h_b, w_b, fmaf(h_c, w_c, fmaf(h_d, w_d, aF[n]))));
            aR[n] = fmaf(h_a, r_a, fmaf(h_b, r_b, fmaf(h_c, r_c, fmaf(h_d, r_d, aR[n]))));
        }
    }
#pragma unroll
    for (int n = 0; n < 4; ++n) {
        int i = base + nb0 + n;
        if (i < NN) {
            float elp = aF[n] * sAl[l], erp = aF[n] * sAr[l];
#pragma unroll
            for (int m = 16; m >= 1; m >>= 1) {
                elp += __shfl_xor(elp, m);
                erp += __shfl_xor(erp, m);
            }
            if (l == 0) { EL2[i] = elp; ER2[i] = erp; }
            F2[(size_t)i * D2 + l]  = f2bu(aF[n]);
            RS2[(size_t)i * D2 + l] = aR[n];
        }
    }
}

// ---------------- layer-2 gather (4-way unrolled chains) + BN2/ReLU + decoder ----------------
__global__ __launch_bounds__(256) void k_final(
        const void* Wd1, const void* Wd2, const void* bd2,
        const int* __restrict__ flag, const float* __restrict__ cst,
        const int* __restrict__ loc, const int* __restrict__ carry,
        const int* __restrict__ esrc,
        const unsigned short* __restrict__ F2, float* __restrict__ RS2,
        const float* __restrict__ EL2, const float* __restrict__ ER2,
        float* __restrict__ out) {
    __shared__ float sWd1[C1 * D2];   // Wd1 [32,128] row-major: idx d*128+j
    __shared__ float sWd2[C1];
    __shared__ float sSd[C1], sRd[C1];
    __shared__ float sSc2[D2], sRc2[D2];
    __shared__ float sH2[8 * D2];     // 8 nodes x 32 dims, same-wave exchange only
    int t = threadIdx.x;
    int bf = *flag;
    for (int u = t; u < C1 * D2; u += 256) sWd1[u] = ldw(Wd1, u, bf);
    for (int u = t; u < C1; u += 256) {
        sWd2[u] = ldw(Wd2, u, bf);
        sSd[u] = cst[CST_SD + u]; sRd[u] = cst[CST_RD + u];
    }
    if (t < D2) { sSc2[t] = cst[CST_SC2 + t]; sRc2[t] = cst[CST_RC2 + t]; }
    __syncthreads();

    int i = (blockIdx.x * 256 + t) >> 5;   // grid exact: 6250 blocks x 8 nodes = 50000
    int l = t & 31;
    int nb = t >> 5;

    // --- edge gather, 4-way unrolled: four independent esrc->EL2->F2 chains in flight
    float eri = ER2[i];
    int e0 = offat(loc, carry, i);
    int e1 = (i + 1 < NN) ? offat(loc, carry, i + 1) : NE;
    float aF0 = 0.0f, aF1 = 0.0f, aF2 = 0.0f, aF3 = 0.0f;
    float S0 = 0.0f, S1 = 0.0f, S2 = 0.0f, S3 = 0.0f;
    int e = e0;
    for (; e + 3 < e1; e += 4) {
        int sA = esrc[e];
        int sB = esrc[e + 1];
        int sC = esrc[e + 2];
        int sD = esrc[e + 3];
        float wA = __expf(lrelu(EL2[sA] + eri));
        float wB = __expf(lrelu(EL2[sB] + eri));
        float wC = __expf(lrelu(EL2[sC] + eri));
        float wD = __expf(lrelu(EL2[sD] + eri));
        float vA = bu2f(F2[(size_t)sA * D2 + l]);
        float vB = bu2f(F2[(size_t)sB * D2 + l]);
        float vC = bu2f(F2[(size_t)sC * D2 + l]);
        float vD = bu2f(F2[(size_t)sD * D2 + l]);
        S0 += wA; S1 += wB; S2 += wC; S3 += wD;
        aF0 = fmaf(wA, vA, aF0);
        aF1 = fmaf(wB, vB, aF1);
        aF2 = fmaf(wC, vC, aF2);
        aF3 = fmaf(wD, vD, aF3);
    }
    for (; e < e1; ++e) {
        int sA = esrc[e];
        float wA = __expf(lrelu(EL2[sA] + eri));
        S0 += wA;
        aF0 = fmaf(wA, bu2f(F2[(size_t)sA * D2 + l]), aF0);
    }
    float S = (S0 + S1) + (S2 + S3);
    float aF = (aF0 + aF1) + (aF2 + aF3);
    float inv = S > 0.0f ? 1.0f / S : 0.0f;

    // --- h2 = relu(BN2(rst + resid)); overwrite RS2 in place (pool kernel reads it)
    float h2 = fmaxf((aF * inv + RS2[(size_t)i * D2 + l]) * sSc2[l] + sRc2[l], 0.0f);
    RS2[(size_t)i * D2 + l] = h2;

    // --- decoder: lane j handles j, j+32, j+64, j+96; h2 via same-wave LDS exchange (no barrier)
    sH2[nb * D2 + l] = h2;
    float rec = 0.0f;
#pragma unroll
    for (int jj = 0; jj < 4; ++jj) {
        int j = l + jj * 32;
        float acc = 0.0f;
#pragma unroll
        for (int d = 0; d < D2; ++d)
            acc = fmaf(sH2[nb * D2 + d], sWd1[d * C1 + j], acc);
        float dj = fmaxf(acc * sSd[j] + sRd[j], 0.0f);
        rec = fmaf(dj, sWd2[j], rec);
    }
#pragma unroll
    for (int m = 16; m >= 1; m >>= 1) rec += __shfl_xor(rec, m);
    if (l == 0) out[NG * D2 + i] = rec + ldw(bd2, 0, bf);
}

// ---------------- graph mean pool: one block per graph, zero atomics ----------------
__global__ __launch_bounds__(256) void k_pool2(const int* __restrict__ gid,
                                               const float* __restrict__ H2,
                                               float* __restrict__ out) {
    __shared__ int sLo, sHi;
    __shared__ float sAcc[8 * D2];
    int g = blockIdx.x;          // 64 graphs
    int t = threadIdx.x;         // 256 threads
    if (t == 0) {
        int lo = 0, hi = NN;
        while (lo < hi) { int m = (lo + hi) >> 1; if (gid[m] < g) lo = m + 1; else hi = m; }
        sLo = lo;
        lo = 0; hi = NN;
        while (lo < hi) { int m = (lo + hi) >> 1; if (gid[m] < g + 1) lo = m + 1; else hi = m; }
        sHi = lo;
    }
    __syncthreads();
    int lo = sLo, hi = sHi;
    int l = t & 31, row = t >> 5;
    float acc = 0.0f;
    for (int i = lo + row; i < hi; i += 8)
        acc += H2[(size_t)i * D2 + l];
    sAcc[row * D2 + l] = acc;
    __syncthreads();
    if (row == 0) {
#pragma unroll
        for (int r = 1; r < 8; ++r) acc += sAcc[r * D2 + l];
        float c = (float)(hi - lo);
        out[g * D2 + l] = acc / fmaxf(c, 1.0f);
    }
}

extern "C" void kernel_launch(void* const* d_in, const int* in_sizes, int n_in,
                              void* d_out, int out_size, void* d_ws, size_t ws_size,
                              hipStream_t stream) {
    const void* feat = d_in[0];
    const void* W1 = d_in[1];  const void* al1 = d_in[2];  const void* ar1 = d_in[3];
    const void* res1 = d_in[4]; const void* b1 = d_in[5];
    const void* g1g = d_in[6]; const void* g1b = d_in[7];
    const void* g1m = d_in[8]; const void* g1v = d_in[9];
    const void* W2 = d_in[10]; const void* al2 = d_in[11]; const void* ar2 = d_in[12];
    const void* res2 = d_in[13]; const void* b2v = d_in[14];
    const void* g2g = d_in[15]; const void* g2b = d_in[16];
    const void* g2m = d_in[17]; const void* g2v = d_in[18];
    const void* Wd1 = d_in[19]; const void* bd1 = d_in[20];
    const void* gdg = d_in[21]; const void* gdb = d_in[22];
    const void* gdm = d_in[23]; const void* gdv = d_in[24];
    const void* Wd2 = d_in[25]; const void* bd2 = d_in[26];
    const int* src = (const int*)d_in[27];
    const int* dst = (const int*)d_in[28];
    const int* gid = (const int*)d_in[29];

    unsigned int* wsu = (unsigned int*)d_ws;
    int* deg    = (int*)(wsu + UO_DEG);
    int* cur    = (int*)(wsu + UO_CUR);
    int* flag   = (int*)(wsu + UO_FLAG);
    int* loc    = (int*)(wsu + UO_LOC);
    int* bsum   = (int*)(wsu + UO_BSUM);
    int* carry  = (int*)(wsu + UO_CARRY);
    int* esrc   = (int*)(wsu + UO_ESRC);
    float* fcan = (float*)(wsu + UO_FCAN);
    float* cst  = (float*)(wsu + UO_CST);
    unsigned short* F2 = (unsigned short*)(wsu + UO_F2);
    float* RS2  = (float*)(wsu + UO_RS2);
    float* EL2  = (float*)(wsu + UO_EL2);
    float* ER2  = (float*)(wsu + UO_ER2);

    hipMemsetAsync(d_ws, 0, (size_t)ZERO_UNITS * 4, stream);

    k_const<<<1, 128, 0, stream>>>(feat, W1, al1, ar1, res1, b1, g1g, g1b, g1m, g1v,
                                   b2v, g2g, g2b, g2m, g2v,
                                   bd1, gdg, gdb, gdm, gdv, flag, cst);

    k_prep<<<(NE + 255) / 256, 256, 0, stream>>>(feat, dst, fcan, deg);
    k_scanA<<<NB, 256, 0, stream>>>(deg, loc, bsum);
    k_scanB<<<1, 256, 0, stream>>>(bsum, carry);
    k_fill<<<(NE + 255) / 256, 256, 0, stream>>>(src, dst, loc, carry, cur, esrc);

    k_layer1<<<(NN + 31) / 32, 256, 0, stream>>>(fcan, W2, res2, al2, ar2, flag, cst,
                                                 loc, carry, esrc, F2, RS2, EL2, ER2);

    k_final<<<(NN * 32) / 256, 256, 0, stream>>>(Wd1, Wd2, bd2, flag, cst,
                                                 loc, carry, esrc, F2, RS2, EL2, ER2,
                                                 (float*)d_out);

    k_pool2<<<NG, 256, 0, stream>>>(gid, RS2, (float*)d_out);
}

// Round 14
// 331.053 us; speedup vs baseline: 1.0359x; 1.0359x over previous
//
#include <hip/hip_runtime.h>
#include <hip/hip_bf16.h>

#define NN 50000
#define NE 800000
#define NG 64
#define C1 128    // H1*D1
#define D2 32
#define NB 196    // (NN+255)/256 scan blocks
#define BN_EPS 1e-5f

// ---- constant-block layout (float offsets inside cst) ----
#define CST_A   0
#define CST_B   2
#define CST_P   4
#define CST_Q   132
#define CST_R   260
#define CST_SC2 388
#define CST_RC2 420
#define CST_SD  452
#define CST_RD  580
#define CST_N   1024

// ---- workspace layout (4-byte-unit offsets inside d_ws), total ~14.0 MiB ----
#define UO_DEG   0                        // int[NN]   (zeroed)
#define UO_CUR   50000                    // int[NN]   (zeroed)
#define UO_CNT   100000                   // int[4]    (zeroed) scanA last-block counter
#define ZERO_UNITS 100004
#define UO_FLAG  100004                   // int[1]
#define UO_LOC   100008                   // int[NN]
#define UO_BSUM  150008                   // int[256]
#define UO_CARRY 150264                   // int[256]
#define UO_ESRC  150520                   // int[NE]
#define UO_FCAN  950520                   // float[NN]
#define UO_CST   1000520                  // float[CST_N]
#define UO_F2    1001544                  // ushort[D2*NN] bf16 (16B aligned)
#define UO_RS2   1801544                  // float[D2*NN]; overwritten with h2 by k_final
#define UO_EL2   3401544                  // float[NN]
#define UO_ER2   3451544                  // float[NN]
#define UO_END   3501544

__device__ __forceinline__ float lrelu(float x) { return x > 0.0f ? x : 0.2f * x; }
__device__ __forceinline__ float bu2f(unsigned int u) {
    union { unsigned int i; float f; } v; v.i = (u & 0xFFFFu) << 16; return v.f;
}
__device__ __forceinline__ unsigned short f2bu(float f) {
    union { float f; unsigned int i; } v; v.f = f;
    unsigned int r = v.i + 0x7FFFu + ((v.i >> 16) & 1u);
    return (unsigned short)(r >> 16);
}
__device__ __forceinline__ float pk_lo(unsigned int w) {
    union { unsigned int i; float f; } v; v.i = w << 16; return v.f;
}
__device__ __forceinline__ float pk_hi(unsigned int w) {
    union { unsigned int i; float f; } v; v.i = w & 0xFFFF0000u; return v.f;
}
__device__ __forceinline__ float ldw(const void* p, int i, int bf) {
    return bf ? bu2f(((const unsigned short*)p)[i]) : ((const float*)p)[i];
}
__device__ __forceinline__ int offat(const int* loc, const int* carry, int i) {
    return loc[i] + carry[i >> 8];
}
__device__ __forceinline__ int sniff64(const unsigned int* fw, int l) {
    int cnt = 0;
    for (int j = l; j < 256; j += 64) {
        unsigned int b = (fw[j] >> 8) & 0x7Fu;
        cnt += (b >= 0x3Au && b <= 0x41u) ? 1 : 0;
    }
#pragma unroll
    for (int m = 32; m >= 1; m >>= 1) cnt += __shfl_xor(cnt, m);
    return (cnt > 128) ? 1 : 0;
}

// ---------------- fcan convert + degree histogram + (block 0) constant folding ----------------
__global__ void k_prep(const void* __restrict__ feat, const int* __restrict__ dst,
                       float* __restrict__ fcan, int* __restrict__ deg,
                       const void* W1, const void* al1, const void* ar1,
                       const void* res1, const void* b1,
                       const void* g1g, const void* g1b, const void* g1m, const void* g1v,
                       const void* b2v, const void* g2g, const void* g2b,
                       const void* g2m, const void* g2v,
                       const void* bd1, const void* gdg, const void* gdb,
                       const void* gdm, const void* gdv,
                       int* __restrict__ flag, float* __restrict__ cst) {
    __shared__ int sBf;
    int t = threadIdx.x;
    if (t < 64) {
        int bf = sniff64((const unsigned int*)feat, t);
        if (t == 0) sBf = bf;
    }
    __syncthreads();
    int bf = sBf;

    if (blockIdx.x == 0) {             // fold tiny weights into fp32 constants
        if (t == 0) *flag = bf;
        if (t < 128) {
            if (t < 2) {
                float a = 0.0f, b = 0.0f;
                for (int d = 0; d < 64; ++d) {
                    float w = ldw(W1, t * 64 + d, bf);
                    a += w * ldw(al1, t * 64 + d, bf);
                    b += w * ldw(ar1, t * 64 + d, bf);
                }
                cst[CST_A + t] = a;
                cst[CST_B + t] = b;
            }
            {
                float sc = rsqrtf(ldw(g1v, t, bf) + BN_EPS) * ldw(g1g, t, bf);
                cst[CST_P + t] = ldw(W1, t, bf) * sc;
                cst[CST_Q + t] = ldw(res1, t, bf) * sc;
                cst[CST_R + t] = (ldw(b1, t, bf) - ldw(g1m, t, bf)) * sc + ldw(g1b, t, bf);
            }
            if (t < D2) {
                float sc = rsqrtf(ldw(g2v, t, bf) + BN_EPS) * ldw(g2g, t, bf);
                cst[CST_SC2 + t] = sc;
                cst[CST_RC2 + t] = (ldw(b2v, t, bf) - ldw(g2m, t, bf)) * sc + ldw(g2b, t, bf);
            }
            {
                float sc = rsqrtf(ldw(gdv, t, bf) + BN_EPS) * ldw(gdg, t, bf);
                cst[CST_SD + t] = sc;
                cst[CST_RD + t] = (ldw(bd1, t, bf) - ldw(gdm, t, bf)) * sc + ldw(gdb, t, bf);
            }
        }
    }

    int k = blockIdx.x * blockDim.x + t;
    if (k < NN) fcan[k] = ldw(feat, k, bf);
    if (k < NE) atomicAdd(&deg[dst[k]], 1);
}

// ---------------- scan: per-block exclusive scan + last-block does the carry scan ----------------
__global__ __launch_bounds__(256) void k_scanA(const int* __restrict__ deg,
                                               int* __restrict__ loc,
                                               int* __restrict__ bsum,
                                               int* __restrict__ carry,
                                               int* __restrict__ cnt) {
    __shared__ int tmp[256];
    __shared__ int isLast;
    int t = threadIdx.x;
    int i = blockIdx.x * 256 + t;
    int v = (i < NN) ? deg[i] : 0;
    tmp[t] = v;
    __syncthreads();
    for (int off = 1; off < 256; off <<= 1) {
        int u = (t >= off) ? tmp[t - off] : 0;
        __syncthreads();
        tmp[t] += u;
        __syncthreads();
    }
    if (i < NN) loc[i] = tmp[t] - v;
    if (t == 255) {
        bsum[blockIdx.x] = tmp[255];
        __threadfence();
        int old = atomicAdd(cnt, 1);
        isLast = (old == NB - 1) ? 1 : 0;
    }
    __syncthreads();
    if (isLast) {                      // final block scans the 196 block sums
        __threadfence();
        int bv = (t < NB) ? bsum[t] : 0;
        tmp[t] = bv;
        __syncthreads();
        for (int off = 1; off < 256; off <<= 1) {
            int u = (t >= off) ? tmp[t - off] : 0;
            __syncthreads();
            tmp[t] += u;
            __syncthreads();
        }
        carry[t] = tmp[t] - bv;
    }
}

// ---------------- CSR fill ----------------
__global__ void k_fill(const int* __restrict__ src, const int* __restrict__ dst,
                       const int* __restrict__ loc, const int* __restrict__ carry,
                       int* __restrict__ cur, int* __restrict__ esrc) {
    int k = blockIdx.x * blockDim.x + threadIdx.x;
    if (k >= NE) return;
    int d = dst[k];
    int pos = offat(loc, carry, d) + atomicAdd(&cur[d], 1);
    esrc[pos] = src[k];
}

// ---------------- layer-1: 32 nodes/block; interleaved phase-1 chains + packed projection ----------------
__global__ __launch_bounds__(256) void k_layer1(
        const float* __restrict__ fcan, const void* W2, const void* res2,
        const void* al2, const void* ar2,
        const int* __restrict__ flag, const float* __restrict__ cst,
        const int* __restrict__ loc, const int* __restrict__ carry,
        const int* __restrict__ esrc,
        unsigned short* __restrict__ F2, float* __restrict__ RS2,
        float* __restrict__ EL2, float* __restrict__ ER2) {
    __shared__ unsigned int sW2pk[32 * 66];  // [l][cw], (c,c+64) bf16 pairs
    __shared__ unsigned int sR2pk[32 * 66];
    __shared__ unsigned int sH1pk[32 * 66];
    __shared__ float sP[C1], sQ[C1], sR[C1];
    __shared__ float sAl[D2], sAr[D2];
    int t = threadIdx.x;
    int bf = *flag;
    // coalesced staging: consecutive t -> consecutive dim l2 (global stride 1)
    for (int u = t; u < 2048; u += 256) {
        int cw = u >> 5, l2 = u & 31;
        unsigned int wlo = (unsigned int)f2bu(ldw(W2, cw * D2 + l2, bf));
        unsigned int whi = (unsigned int)f2bu(ldw(W2, (cw + 64) * D2 + l2, bf));
        sW2pk[l2 * 66 + cw] = wlo | (whi << 16);
        unsigned int rlo = (unsigned int)f2bu(ldw(res2, cw * D2 + l2, bf));
        unsigned int rhi = (unsigned int)f2bu(ldw(res2, (cw + 64) * D2 + l2, bf));
        sR2pk[l2 * 66 + cw] = rlo | (rhi << 16);
    }
    if (t < C1) { sP[t] = cst[CST_P + t]; sQ[t] = cst[CST_Q + t]; sR[t] = cst[CST_R + t]; }
    if (t < D2) { sAl[t] = ldw(al2, t, bf); sAr[t] = ldw(ar2, t, bf); }
    __syncthreads();

    int l = t & 31;
    int g = t >> 5;
    int base = blockIdx.x * 32;
    float A0 = cst[CST_A + 0], A1 = cst[CST_A + 1];
    float B0 = cst[CST_B + 0], B1 = cst[CST_B + 1];

    // --- phase 1: 4 nodes per group with INTERLEAVED independent load chains
    int e0k[4], e1k[4];
    float fiK[4];
#pragma unroll
    for (int k = 0; k < 4; ++k) {
        int i = base + g * 4 + k;
        if (i < NN) {
            e0k[k] = offat(loc, carry, i);
            e1k[k] = (i + 1 < NN) ? offat(loc, carry, i + 1) : NE;
            fiK[k] = fcan[i];
        } else { e0k[k] = 0; e1k[k] = 0; fiK[k] = 0.0f; }
    }
    float S0[4], S1[4], N0[4], N1[4];
#pragma unroll
    for (int k = 0; k < 4; ++k) { S0[k] = S1[k] = N0[k] = N1[k] = 0.0f; }
    // first 32 edges of each node: 4 chains in flight
    int sA[4];
#pragma unroll
    for (int k = 0; k < 4; ++k) sA[k] = (e0k[k] + l < e1k[k]) ? esrc[e0k[k] + l] : 0;
    float fA[4];
#pragma unroll
    for (int k = 0; k < 4; ++k) fA[k] = fcan[sA[k]];
#pragma unroll
    for (int k = 0; k < 4; ++k) {
        if (e0k[k] + l < e1k[k]) {
            float w0 = __expf(lrelu(A0 * fA[k] + B0 * fiK[k]));
            float w1 = __expf(lrelu(A1 * fA[k] + B1 * fiK[k]));
            S0[k] += w0; N0[k] += w0 * fA[k];
            S1[k] += w1; N1[k] += w1 * fA[k];
        }
    }
    // rare cleanup for deg > 32
#pragma unroll
    for (int k = 0; k < 4; ++k) {
        for (int e = e0k[k] + l + 32; e < e1k[k]; e += 32) {
            int s = esrc[e];
            float fs = fcan[s];
            float w0 = __expf(lrelu(A0 * fs + B0 * fiK[k]));
            float w1 = __expf(lrelu(A1 * fs + B1 * fiK[k]));
            S0[k] += w0; N0[k] += w0 * fs;
            S1[k] += w1; N1[k] += w1 * fs;
        }
    }
    // interleaved reductions (4 independent chains per level)
#pragma unroll
    for (int m = 16; m >= 1; m >>= 1) {
#pragma unroll
        for (int k = 0; k < 4; ++k) {
            S0[k] += __shfl_xor(S0[k], m); N0[k] += __shfl_xor(N0[k], m);
            S1[k] += __shfl_xor(S1[k], m); N1[k] += __shfl_xor(N1[k], m);
        }
    }
#pragma unroll
    for (int k = 0; k < 4; ++k) {
        int slot = g * 4 + k;
        float T0 = S0[k] > 0.0f ? N0[k] / S0[k] : 0.0f;
        float T1 = S1[k] > 0.0f ? N1[k] / S1[k] : 0.0f;
        float h0  = fmaxf(sP[l]      * T0 + sQ[l]      * fiK[k] + sR[l],      0.0f);
        float h1v = fmaxf(sP[l + 32] * T0 + sQ[l + 32] * fiK[k] + sR[l + 32], 0.0f);
        float h2v = fmaxf(sP[l + 64] * T1 + sQ[l + 64] * fiK[k] + sR[l + 64], 0.0f);
        float h3v = fmaxf(sP[l + 96] * T1 + sQ[l + 96] * fiK[k] + sR[l + 96], 0.0f);
        sH1pk[slot * 66 + l]      = (unsigned int)f2bu(h0)  | ((unsigned int)f2bu(h2v) << 16);
        sH1pk[slot * 66 + l + 32] = (unsigned int)f2bu(h1v) | ((unsigned int)f2bu(h3v) << 16);
    }
    __syncthreads();

    // --- phase 2: wave owns 8 nodes; half-wave lane keeps 4 nodes in registers
    int w = t >> 6;
    int half = (t >> 5) & 1;
    int nb0 = w * 8 + half * 4;
    float aF[4] = {0.f, 0.f, 0.f, 0.f}, aR[4] = {0.f, 0.f, 0.f, 0.f};
    for (int cw = 0; cw < 64; cw += 2) {
        uint2 wq = *(const uint2*)&sW2pk[l * 66 + cw];
        uint2 rq = *(const uint2*)&sR2pk[l * 66 + cw];
        float w_a = pk_lo(wq.x), w_b = pk_hi(wq.x), w_c = pk_lo(wq.y), w_d = pk_hi(wq.y);
        float r_a = pk_lo(rq.x), r_b = pk_hi(rq.x), r_c = pk_lo(rq.y), r_d = pk_hi(rq.y);
#pragma unroll
        for (int n = 0; n < 4; ++n) {
            uint2 hq = *(const uint2*)&sH1pk[(nb0 + n) * 66 + cw];
            float h_a = pk_lo(hq.x), h_b = pk_hi(hq.x), h_c = pk_lo(hq.y), h_d = pk_hi(hq.y);
            aF[n] = fmaf(h_a, w_a, fmaf(h_b, w_b, fmaf(h_c, w_c, fmaf(h_d, w_d, aF[n]))));
            aR[n] = fmaf(h_a, r_a, fmaf(h_b, r_b, fmaf(h_c, r_c, fmaf(h_d, r_d, aR[n]))));
        }
    }
#pragma unroll
    for (int n = 0; n < 4; ++n) {
        int i = base + nb0 + n;
        if (i < NN) {
            float elp = aF[n] * sAl[l], erp = aF[n] * sAr[l];
#pragma unroll
            for (int m = 16; m >= 1; m >>= 1) {
                elp += __shfl_xor(elp, m);
                erp += __shfl_xor(erp, m);
            }
            if (l == 0) { EL2[i] = elp; ER2[i] = erp; }
            F2[(size_t)i * D2 + l]  = f2bu(aF[n]);
            RS2[(size_t)i * D2 + l] = aR[n];
        }
    }
}

// ---------------- layer-2 gather (4-way unrolled chains) + BN2/ReLU + decoder ----------------
__global__ __launch_bounds__(256) void k_final(
        const void* Wd1, const void* Wd2, const void* bd2,
        const int* __restrict__ flag, const float* __restrict__ cst,
        const int* __restrict__ loc, const int* __restrict__ carry,
        const int* __restrict__ esrc,
        const unsigned short* __restrict__ F2, float* __restrict__ RS2,
        const float* __restrict__ EL2, const float* __restrict__ ER2,
        float* __restrict__ out) {
    __shared__ float sWd1[C1 * D2];
    __shared__ float sWd2[C1];
    __shared__ float sSd[C1], sRd[C1];
    __shared__ float sSc2[D2], sRc2[D2];
    __shared__ float sH2[8 * D2];
    int t = threadIdx.x;
    int bf = *flag;
    for (int u = t; u < C1 * D2; u += 256) sWd1[u] = ldw(Wd1, u, bf);
    for (int u = t; u < C1; u += 256) {
        sWd2[u] = ldw(Wd2, u, bf);
        sSd[u] = cst[CST_SD + u]; sRd[u] = cst[CST_RD + u];
    }
    if (t < D2) { sSc2[t] = cst[CST_SC2 + t]; sRc2[t] = cst[CST_RC2 + t]; }
    __syncthreads();

    int i = (blockIdx.x * 256 + t) >> 5;
    int l = t & 31;
    int nb = t >> 5;

    float eri = ER2[i];
    int e0 = offat(loc, carry, i);
    int e1 = (i + 1 < NN) ? offat(loc, carry, i + 1) : NE;
    float aF0 = 0.0f, aF1 = 0.0f, aF2 = 0.0f, aF3 = 0.0f;
    float S0 = 0.0f, S1 = 0.0f, S2 = 0.0f, S3 = 0.0f;
    int e = e0;
    for (; e + 3 < e1; e += 4) {
        int sA = esrc[e];
        int sB = esrc[e + 1];
        int sC = esrc[e + 2];
        int sD = esrc[e + 3];
        float wA = __expf(lrelu(EL2[sA] + eri));
        float wB = __expf(lrelu(EL2[sB] + eri));
        float wC = __expf(lrelu(EL2[sC] + eri));
        float wD = __expf(lrelu(EL2[sD] + eri));
        float vA = bu2f(F2[(size_t)sA * D2 + l]);
        float vB = bu2f(F2[(size_t)sB * D2 + l]);
        float vC = bu2f(F2[(size_t)sC * D2 + l]);
        float vD = bu2f(F2[(size_t)sD * D2 + l]);
        S0 += wA; S1 += wB; S2 += wC; S3 += wD;
        aF0 = fmaf(wA, vA, aF0);
        aF1 = fmaf(wB, vB, aF1);
        aF2 = fmaf(wC, vC, aF2);
        aF3 = fmaf(wD, vD, aF3);
    }
    for (; e < e1; ++e) {
        int sA = esrc[e];
        float wA = __expf(lrelu(EL2[sA] + eri));
        S0 += wA;
        aF0 = fmaf(wA, bu2f(F2[(size_t)sA * D2 + l]), aF0);
    }
    float S = (S0 + S1) + (S2 + S3);
    float aF = (aF0 + aF1) + (aF2 + aF3);
    float inv = S > 0.0f ? 1.0f / S : 0.0f;

    float h2 = fmaxf((aF * inv + RS2[(size_t)i * D2 + l]) * sSc2[l] + sRc2[l], 0.0f);
    RS2[(size_t)i * D2 + l] = h2;

    sH2[nb * D2 + l] = h2;
    float rec = 0.0f;
#pragma unroll
    for (int jj = 0; jj < 4; ++jj) {
        int j = l + jj * 32;
        float acc = 0.0f;
#pragma unroll
        for (int d = 0; d < D2; ++d)
            acc = fmaf(sH2[nb * D2 + d], sWd1[d * C1 + j], acc);
        float dj = fmaxf(acc * sSd[j] + sRd[j], 0.0f);
        rec = fmaf(dj, sWd2[j], rec);
    }
#pragma unroll
    for (int m = 16; m >= 1; m >>= 1) rec += __shfl_xor(rec, m);
    if (l == 0) out[NG * D2 + i] = rec + ldw(bd2, 0, bf);
}

// ---------------- graph mean pool: one block per graph, zero atomics ----------------
__global__ __launch_bounds__(256) void k_pool2(const int* __restrict__ gid,
                                               const float* __restrict__ H2,
                                               float* __restrict__ out) {
    __shared__ int sLo, sHi;
    __shared__ float sAcc[8 * D2];
    int g = blockIdx.x;
    int t = threadIdx.x;
    if (t == 0) {
        int lo = 0, hi = NN;
        while (lo < hi) { int m = (lo + hi) >> 1; if (gid[m] < g) lo = m + 1; else hi = m; }
        sLo = lo;
        lo = 0; hi = NN;
        while (lo < hi) { int m = (lo + hi) >> 1; if (gid[m] < g + 1) lo = m + 1; else hi = m; }
        sHi = lo;
    }
    __syncthreads();
    int lo = sLo, hi = sHi;
    int l = t & 31, row = t >> 5;
    float acc = 0.0f;
    for (int i = lo + row; i < hi; i += 8)
        acc += H2[(size_t)i * D2 + l];
    sAcc[row * D2 + l] = acc;
    __syncthreads();
    if (row == 0) {
#pragma unroll
        for (int r = 1; r < 8; ++r) acc += sAcc[r * D2 + l];
        float c = (float)(hi - lo);
        out[g * D2 + l] = acc / fmaxf(c, 1.0f);
    }
}

extern "C" void kernel_launch(void* const* d_in, const int* in_sizes, int n_in,
                              void* d_out, int out_size, void* d_ws, size_t ws_size,
                              hipStream_t stream) {
    const void* feat = d_in[0];
    const void* W1 = d_in[1];  const void* al1 = d_in[2];  const void* ar1 = d_in[3];
    const void* res1 = d_in[4]; const void* b1 = d_in[5];
    const void* g1g = d_in[6]; const void* g1b = d_in[7];
    const void* g1m = d_in[8]; const void* g1v = d_in[9];
    const void* W2 = d_in[10]; const void* al2 = d_in[11]; const void* ar2 = d_in[12];
    const void* res2 = d_in[13]; const void* b2v = d_in[14];
    const void* g2g = d_in[15]; const void* g2b = d_in[16];
    const void* g2m = d_in[17]; const void* g2v = d_in[18];
    const void* Wd1 = d_in[19]; const void* bd1 = d_in[20];
    const void* gdg = d_in[21]; const void* gdb = d_in[22];
    const void* gdm = d_in[23]; const void* gdv = d_in[24];
    const void* Wd2 = d_in[25]; const void* bd2 = d_in[26];
    const int* src = (const int*)d_in[27];
    const int* dst = (const int*)d_in[28];
    const int* gid = (const int*)d_in[29];

    unsigned int* wsu = (unsigned int*)d_ws;
    int* deg    = (int*)(wsu + UO_DEG);
    int* cur    = (int*)(wsu + UO_CUR);
    int* cnt    = (int*)(wsu + UO_CNT);
    int* flag   = (int*)(wsu + UO_FLAG);
    int* loc    = (int*)(wsu + UO_LOC);
    int* bsum   = (int*)(wsu + UO_BSUM);
    int* carry  = (int*)(wsu + UO_CARRY);
    int* esrc   = (int*)(wsu + UO_ESRC);
    float* fcan = (float*)(wsu + UO_FCAN);
    float* cst  = (float*)(wsu + UO_CST);
    unsigned short* F2 = (unsigned short*)(wsu + UO_F2);
    float* RS2  = (float*)(wsu + UO_RS2);
    float* EL2  = (float*)(wsu + UO_EL2);
    float* ER2  = (float*)(wsu + UO_ER2);

    hipMemsetAsync(d_ws, 0, (size_t)ZERO_UNITS * 4, stream);

    k_prep<<<(NE + 255) / 256, 256, 0, stream>>>(feat, dst, fcan, deg,
                                                 W1, al1, ar1, res1, b1,
                                                 g1g, g1b, g1m, g1v,
                                                 b2v, g2g, g2b, g2m, g2v,
                                                 bd1, gdg, gdb, gdm, gdv,
                                                 flag, cst);
    k_scanA<<<NB, 256, 0, stream>>>(deg, loc, bsum, carry, cnt);
    k_fill<<<(NE + 255) / 256, 256, 0, stream>>>(src, dst, loc, carry, cur, esrc);

    k_layer1<<<(NN + 31) / 32, 256, 0, stream>>>(fcan, W2, res2, al2, ar2, flag, cst,
                                                 loc, carry, esrc, F2, RS2, EL2, ER2);

    k_final<<<(NN * 32) / 256, 256, 0, stream>>>(Wd1, Wd2, bd2, flag, cst,
                                                 loc, carry, esrc, F2, RS2, EL2, ER2,
                                                 (float*)d_out);

    k_pool2<<<NG, 256, 0, stream>>>(gid, RS2, (float*)d_out);
}

// Round 15
// 293.359 us; speedup vs baseline: 1.1690x; 1.1285x over previous
//
#include <hip/hip_runtime.h>
#include <hip/hip_bf16.h>

#define NN 50000
#define NE 800000
#define NG 64
#define C1 128    // H1*D1
#define D2 32
#define NB 196    // (NN+255)/256 scan blocks
#define BN_EPS 1e-5f

// ---- constant-block layout (float offsets inside cst) ----
#define CST_A   0
#define CST_B   2
#define CST_P   4
#define CST_Q   132
#define CST_R   260
#define CST_SC2 388
#define CST_RC2 420
#define CST_SD  452
#define CST_RD  580
#define CST_N   1024

// ---- workspace layout (4-byte-unit offsets inside d_ws), total ~17.0 MiB (ws is 256 MB) ----
#define UO_DEG   0                        // int[NN]  (zeroed)
#define UO_CNT   50000                    // int[4]   (zeroed) scanA last-block counter
#define ZERO_UNITS 50004
#define UO_FLAG  50004                    // int[1]
#define UO_LOC   50008                    // int[NN]
#define UO_BSUM  100008                   // int[256]
#define UO_CARRY 100264                   // int[256]
#define UO_ESRC  100520                   // int[NE]
#define UO_EOFF  900520                   // int[NE]  slot-within-node from k_prep atomic
#define UO_FCAN  1700520                  // float[NN]
#define UO_CST   1750520                  // float[CST_N]
#define UO_F2    1751544                  // ushort[D2*NN] bf16 (16B aligned)
#define UO_RS2   2551544                  // float[D2*NN]; overwritten with h2 by k_final
#define UO_EL2   4151544                  // float[NN]
#define UO_ER2   4201544                  // float[NN]
#define UO_END   4251544

__device__ __forceinline__ float lrelu(float x) { return x > 0.0f ? x : 0.2f * x; }
__device__ __forceinline__ float bu2f(unsigned int u) {
    union { unsigned int i; float f; } v; v.i = (u & 0xFFFFu) << 16; return v.f;
}
__device__ __forceinline__ unsigned short f2bu(float f) {
    union { float f; unsigned int i; } v; v.f = f;
    unsigned int r = v.i + 0x7FFFu + ((v.i >> 16) & 1u);
    return (unsigned short)(r >> 16);
}
__device__ __forceinline__ float pk_lo(unsigned int w) {
    union { unsigned int i; float f; } v; v.i = w << 16; return v.f;
}
__device__ __forceinline__ float pk_hi(unsigned int w) {
    union { unsigned int i; float f; } v; v.i = w & 0xFFFF0000u; return v.f;
}
__device__ __forceinline__ float ldw(const void* p, int i, int bf) {
    return bf ? bu2f(((const unsigned short*)p)[i]) : ((const float*)p)[i];
}
__device__ __forceinline__ int offat(const int* loc, const int* carry, int i) {
    return loc[i] + carry[i >> 8];
}
__device__ __forceinline__ int sniff64(const unsigned int* fw, int l) {
    int cnt = 0;
    for (int j = l; j < 256; j += 64) {
        unsigned int b = (fw[j] >> 8) & 0x7Fu;
        cnt += (b >= 0x3Au && b <= 0x41u) ? 1 : 0;
    }
#pragma unroll
    for (int m = 32; m >= 1; m >>= 1) cnt += __shfl_xor(cnt, m);
    return (cnt > 128) ? 1 : 0;
}

// ---------------- fcan convert + degree histogram (keeps slot) + (block 0) const folding ----------------
__global__ void k_prep(const void* __restrict__ feat, const int* __restrict__ dst,
                       float* __restrict__ fcan, int* __restrict__ deg,
                       int* __restrict__ eoff,
                       const void* W1, const void* al1, const void* ar1,
                       const void* res1, const void* b1,
                       const void* g1g, const void* g1b, const void* g1m, const void* g1v,
                       const void* b2v, const void* g2g, const void* g2b,
                       const void* g2m, const void* g2v,
                       const void* bd1, const void* gdg, const void* gdb,
                       const void* gdm, const void* gdv,
                       int* __restrict__ flag, float* __restrict__ cst) {
    __shared__ int sBf;
    int t = threadIdx.x;
    if (t < 64) {
        int bf = sniff64((const unsigned int*)feat, t);
        if (t == 0) sBf = bf;
    }
    __syncthreads();
    int bf = sBf;

    if (blockIdx.x == 0) {             // fold tiny weights into fp32 constants
        if (t == 0) *flag = bf;
        if (t < 128) {
            if (t < 2) {
                float a = 0.0f, b = 0.0f;
                for (int d = 0; d < 64; ++d) {
                    float w = ldw(W1, t * 64 + d, bf);
                    a += w * ldw(al1, t * 64 + d, bf);
                    b += w * ldw(ar1, t * 64 + d, bf);
                }
                cst[CST_A + t] = a;
                cst[CST_B + t] = b;
            }
            {
                float sc = rsqrtf(ldw(g1v, t, bf) + BN_EPS) * ldw(g1g, t, bf);
                cst[CST_P + t] = ldw(W1, t, bf) * sc;
                cst[CST_Q + t] = ldw(res1, t, bf) * sc;
                cst[CST_R + t] = (ldw(b1, t, bf) - ldw(g1m, t, bf)) * sc + ldw(g1b, t, bf);
            }
            if (t < D2) {
                float sc = rsqrtf(ldw(g2v, t, bf) + BN_EPS) * ldw(g2g, t, bf);
                cst[CST_SC2 + t] = sc;
                cst[CST_RC2 + t] = (ldw(b2v, t, bf) - ldw(g2m, t, bf)) * sc + ldw(g2b, t, bf);
            }
            {
                float sc = rsqrtf(ldw(gdv, t, bf) + BN_EPS) * ldw(gdg, t, bf);
                cst[CST_SD + t] = sc;
                cst[CST_RD + t] = (ldw(bd1, t, bf) - ldw(gdm, t, bf)) * sc + ldw(gdb, t, bf);
            }
        }
    }

    int k = blockIdx.x * blockDim.x + t;
    if (k < NN) fcan[k] = ldw(feat, k, bf);
    if (k < NE) eoff[k] = atomicAdd(&deg[dst[k]], 1);   // slot within node, free byproduct
}

// ---------------- scan: per-block exclusive scan + last-block does the carry scan ----------------
__global__ __launch_bounds__(256) void k_scanA(const int* __restrict__ deg,
                                               int* __restrict__ loc,
                                               int* __restrict__ bsum,
                                               int* __restrict__ carry,
                                               int* __restrict__ cnt) {
    __shared__ int tmp[256];
    __shared__ int isLast;
    int t = threadIdx.x;
    int i = blockIdx.x * 256 + t;
    int v = (i < NN) ? deg[i] : 0;
    tmp[t] = v;
    __syncthreads();
    for (int off = 1; off < 256; off <<= 1) {
        int u = (t >= off) ? tmp[t - off] : 0;
        __syncthreads();
        tmp[t] += u;
        __syncthreads();
    }
    if (i < NN) loc[i] = tmp[t] - v;
    if (t == 255) {
        bsum[blockIdx.x] = tmp[255];
        __threadfence();
        int old = atomicAdd(cnt, 1);
        isLast = (old == NB - 1) ? 1 : 0;
    }
    __syncthreads();
    if (isLast) {
        __threadfence();
        int bv = (t < NB) ? bsum[t] : 0;
        tmp[t] = bv;
        __syncthreads();
        for (int off = 1; off < 256; off <<= 1) {
            int u = (t >= off) ? tmp[t - off] : 0;
            __syncthreads();
            tmp[t] += u;
            __syncthreads();
        }
        carry[t] = tmp[t] - bv;
    }
}

// ---------------- CSR fill: atomic-free (slot precomputed in k_prep) ----------------
__global__ void k_fill(const int* __restrict__ src, const int* __restrict__ dst,
                       const int* __restrict__ loc, const int* __restrict__ carry,
                       const int* __restrict__ eoff, int* __restrict__ esrc) {
    int k = blockIdx.x * blockDim.x + threadIdx.x;
    if (k >= NE) return;
    int d = dst[k];
    esrc[offat(loc, carry, d) + eoff[k]] = src[k];
}

// ---------------- layer-1: 32 nodes/block; interleaved phase-1 chains + packed projection ----------------
__global__ __launch_bounds__(256) void k_layer1(
        const float* __restrict__ fcan, const void* W2, const void* res2,
        const void* al2, const void* ar2,
        const int* __restrict__ flag, const float* __restrict__ cst,
        const int* __restrict__ loc, const int* __restrict__ carry,
        const int* __restrict__ esrc,
        unsigned short* __restrict__ F2, float* __restrict__ RS2,
        float* __restrict__ EL2, float* __restrict__ ER2) {
    __shared__ unsigned int sW2pk[32 * 66];  // [l][cw], (c,c+64) bf16 pairs
    __shared__ unsigned int sR2pk[32 * 66];
    __shared__ unsigned int sH1pk[32 * 66];
    __shared__ float sP[C1], sQ[C1], sR[C1];
    __shared__ float sAl[D2], sAr[D2];
    int t = threadIdx.x;
    int bf = *flag;
    for (int u = t; u < 2048; u += 256) {
        int cw = u >> 5, l2 = u & 31;
        unsigned int wlo = (unsigned int)f2bu(ldw(W2, cw * D2 + l2, bf));
        unsigned int whi = (unsigned int)f2bu(ldw(W2, (cw + 64) * D2 + l2, bf));
        sW2pk[l2 * 66 + cw] = wlo | (whi << 16);
        unsigned int rlo = (unsigned int)f2bu(ldw(res2, cw * D2 + l2, bf));
        unsigned int rhi = (unsigned int)f2bu(ldw(res2, (cw + 64) * D2 + l2, bf));
        sR2pk[l2 * 66 + cw] = rlo | (rhi << 16);
    }
    if (t < C1) { sP[t] = cst[CST_P + t]; sQ[t] = cst[CST_Q + t]; sR[t] = cst[CST_R + t]; }
    if (t < D2) { sAl[t] = ldw(al2, t, bf); sAr[t] = ldw(ar2, t, bf); }
    __syncthreads();

    int l = t & 31;
    int g = t >> 5;
    int base = blockIdx.x * 32;
    float A0 = cst[CST_A + 0], A1 = cst[CST_A + 1];
    float B0 = cst[CST_B + 0], B1 = cst[CST_B + 1];

    int e0k[4], e1k[4];
    float fiK[4];
#pragma unroll
    for (int k = 0; k < 4; ++k) {
        int i = base + g * 4 + k;
        if (i < NN) {
            e0k[k] = offat(loc, carry, i);
            e1k[k] = (i + 1 < NN) ? offat(loc, carry, i + 1) : NE;
            fiK[k] = fcan[i];
        } else { e0k[k] = 0; e1k[k] = 0; fiK[k] = 0.0f; }
    }
    float S0[4], S1[4], N0[4], N1[4];
#pragma unroll
    for (int k = 0; k < 4; ++k) { S0[k] = S1[k] = N0[k] = N1[k] = 0.0f; }
    int sA[4];
#pragma unroll
    for (int k = 0; k < 4; ++k) sA[k] = (e0k[k] + l < e1k[k]) ? esrc[e0k[k] + l] : 0;
    float fA[4];
#pragma unroll
    for (int k = 0; k < 4; ++k) fA[k] = fcan[sA[k]];
#pragma unroll
    for (int k = 0; k < 4; ++k) {
        if (e0k[k] + l < e1k[k]) {
            float w0 = __expf(lrelu(A0 * fA[k] + B0 * fiK[k]));
            float w1 = __expf(lrelu(A1 * fA[k] + B1 * fiK[k]));
            S0[k] += w0; N0[k] += w0 * fA[k];
            S1[k] += w1; N1[k] += w1 * fA[k];
        }
    }
#pragma unroll
    for (int k = 0; k < 4; ++k) {
        for (int e = e0k[k] + l + 32; e < e1k[k]; e += 32) {
            int s = esrc[e];
            float fs = fcan[s];
            float w0 = __expf(lrelu(A0 * fs + B0 * fiK[k]));
            float w1 = __expf(lrelu(A1 * fs + B1 * fiK[k]));
            S0[k] += w0; N0[k] += w0 * fs;
            S1[k] += w1; N1[k] += w1 * fs;
        }
    }
#pragma unroll
    for (int m = 16; m >= 1; m >>= 1) {
#pragma unroll
        for (int k = 0; k < 4; ++k) {
            S0[k] += __shfl_xor(S0[k], m); N0[k] += __shfl_xor(N0[k], m);
            S1[k] += __shfl_xor(S1[k], m); N1[k] += __shfl_xor(N1[k], m);
        }
    }
#pragma unroll
    for (int k = 0; k < 4; ++k) {
        int slot = g * 4 + k;
        float T0 = S0[k] > 0.0f ? N0[k] / S0[k] : 0.0f;
        float T1 = S1[k] > 0.0f ? N1[k] / S1[k] : 0.0f;
        float h0  = fmaxf(sP[l]      * T0 + sQ[l]      * fiK[k] + sR[l],      0.0f);
        float h1v = fmaxf(sP[l + 32] * T0 + sQ[l + 32] * fiK[k] + sR[l + 32], 0.0f);
        float h2v = fmaxf(sP[l + 64] * T1 + sQ[l + 64] * fiK[k] + sR[l + 64], 0.0f);
        float h3v = fmaxf(sP[l + 96] * T1 + sQ[l + 96] * fiK[k] + sR[l + 96], 0.0f);
        sH1pk[slot * 66 + l]      = (unsigned int)f2bu(h0)  | ((unsigned int)f2bu(h2v) << 16);
        sH1pk[slot * 66 + l + 32] = (unsigned int)f2bu(h1v) | ((unsigned int)f2bu(h3v) << 16);
    }
    __syncthreads();

    int w = t >> 6;
    int half = (t >> 5) & 1;
    int nb0 = w * 8 + half * 4;
    float aF[4] = {0.f, 0.f, 0.f, 0.f}, aR[4] = {0.f, 0.f, 0.f, 0.f};
    for (int cw = 0; cw < 64; cw += 2) {
        uint2 wq = *(const uint2*)&sW2pk[l * 66 + cw];
        uint2 rq = *(const uint2*)&sR2pk[l * 66 + cw];
        float w_a = pk_lo(wq.x), w_b = pk_hi(wq.x), w_c = pk_lo(wq.y), w_d = pk_hi(wq.y);
        float r_a = pk_lo(rq.x), r_b = pk_hi(rq.x), r_c = pk_lo(rq.y), r_d = pk_hi(rq.y);
#pragma unroll
        for (int n = 0; n < 4; ++n) {
            uint2 hq = *(const uint2*)&sH1pk[(nb0 + n) * 66 + cw];
            float h_a = pk_lo(hq.x), h_b = pk_hi(hq.x), h_c = pk_lo(hq.y), h_d = pk_hi(hq.y);
            aF[n] = fmaf(h_a, w_a, fmaf(h_b, w_b, fmaf(h_c, w_c, fmaf(h_d, w_d, aF[n]))));
            aR[n] = fmaf(h_a, r_a, fmaf(h_b, r_b, fmaf(h_c, r_c, fmaf(h_d, r_d, aR[n]))));
        }
    }
#pragma unroll
    for (int n = 0; n < 4; ++n) {
        int i = base + nb0 + n;
        if (i < NN) {
            float elp = aF[n] * sAl[l], erp = aF[n] * sAr[l];
#pragma unroll
            for (int m = 16; m >= 1; m >>= 1) {
                elp += __shfl_xor(elp, m);
                erp += __shfl_xor(erp, m);
            }
            if (l == 0) { EL2[i] = elp; ER2[i] = erp; }
            F2[(size_t)i * D2 + l]  = f2bu(aF[n]);
            RS2[(size_t)i * D2 + l] = aR[n];
        }
    }
}

// ---------------- layer-2 gather (4-way unrolled chains) + BN2/ReLU + decoder ----------------
__global__ __launch_bounds__(256) void k_final(
        const void* Wd1, const void* Wd2, const void* bd2,
        const int* __restrict__ flag, const float* __restrict__ cst,
        const int* __restrict__ loc, const int* __restrict__ carry,
        const int* __restrict__ esrc,
        const unsigned short* __restrict__ F2, float* __restrict__ RS2,
        const float* __restrict__ EL2, const float* __restrict__ ER2,
        float* __restrict__ out) {
    __shared__ float sWd1[C1 * D2];
    __shared__ float sWd2[C1];
    __shared__ float sSd[C1], sRd[C1];
    __shared__ float sSc2[D2], sRc2[D2];
    __shared__ float sH2[8 * D2];
    int t = threadIdx.x;
    int bf = *flag;
    for (int u = t; u < C1 * D2; u += 256) sWd1[u] = ldw(Wd1, u, bf);
    for (int u = t; u < C1; u += 256) {
        sWd2[u] = ldw(Wd2, u, bf);
        sSd[u] = cst[CST_SD + u]; sRd[u] = cst[CST_RD + u];
    }
    if (t < D2) { sSc2[t] = cst[CST_SC2 + t]; sRc2[t] = cst[CST_RC2 + t]; }
    __syncthreads();

    int i = (blockIdx.x * 256 + t) >> 5;
    int l = t & 31;
    int nb = t >> 5;

    float eri = ER2[i];
    int e0 = offat(loc, carry, i);
    int e1 = (i + 1 < NN) ? offat(loc, carry, i + 1) : NE;
    float aF0 = 0.0f, aF1 = 0.0f, aF2 = 0.0f, aF3 = 0.0f;
    float S0 = 0.0f, S1 = 0.0f, S2 = 0.0f, S3 = 0.0f;
    int e = e0;
    for (; e + 3 < e1; e += 4) {
        int sA = esrc[e];
        int sB = esrc[e + 1];
        int sC = esrc[e + 2];
        int sD = esrc[e + 3];
        float wA = __expf(lrelu(EL2[sA] + eri));
        float wB = __expf(lrelu(EL2[sB] + eri));
        float wC = __expf(lrelu(EL2[sC] + eri));
        float wD = __expf(lrelu(EL2[sD] + eri));
        float vA = bu2f(F2[(size_t)sA * D2 + l]);
        float vB = bu2f(F2[(size_t)sB * D2 + l]);
        float vC = bu2f(F2[(size_t)sC * D2 + l]);
        float vD = bu2f(F2[(size_t)sD * D2 + l]);
        S0 += wA; S1 += wB; S2 += wC; S3 += wD;
        aF0 = fmaf(wA, vA, aF0);
        aF1 = fmaf(wB, vB, aF1);
        aF2 = fmaf(wC, vC, aF2);
        aF3 = fmaf(wD, vD, aF3);
    }
    for (; e < e1; ++e) {
        int sA = esrc[e];
        float wA = __expf(lrelu(EL2[sA] + eri));
        S0 += wA;
        aF0 = fmaf(wA, bu2f(F2[(size_t)sA * D2 + l]), aF0);
    }
    float S = (S0 + S1) + (S2 + S3);
    float aF = (aF0 + aF1) + (aF2 + aF3);
    float inv = S > 0.0f ? 1.0f / S : 0.0f;

    float h2 = fmaxf((aF * inv + RS2[(size_t)i * D2 + l]) * sSc2[l] + sRc2[l], 0.0f);
    RS2[(size_t)i * D2 + l] = h2;

    sH2[nb * D2 + l] = h2;
    float rec = 0.0f;
#pragma unroll
    for (int jj = 0; jj < 4; ++jj) {
        int j = l + jj * 32;
        float acc = 0.0f;
#pragma unroll
        for (int d = 0; d < D2; ++d)
            acc = fmaf(sH2[nb * D2 + d], sWd1[d * C1 + j], acc);
        float dj = fmaxf(acc * sSd[j] + sRd[j], 0.0f);
        rec = fmaf(dj, sWd2[j], rec);
    }
#pragma unroll
    for (int m = 16; m >= 1; m >>= 1) rec += __shfl_xor(rec, m);
    if (l == 0) out[NG * D2 + i] = rec + ldw(bd2, 0, bf);
}

// ---------------- graph mean pool: one block per graph, zero atomics ----------------
__global__ __launch_bounds__(256) void k_pool2(const int* __restrict__ gid,
                                               const float* __restrict__ H2,
                                               float* __restrict__ out) {
    __shared__ int sLo, sHi;
    __shared__ float sAcc[8 * D2];
    int g = blockIdx.x;
    int t = threadIdx.x;
    if (t == 0) {
        int lo = 0, hi = NN;
        while (lo < hi) { int m = (lo + hi) >> 1; if (gid[m] < g) lo = m + 1; else hi = m; }
        sLo = lo;
        lo = 0; hi = NN;
        while (lo < hi) { int m = (lo + hi) >> 1; if (gid[m] < g + 1) lo = m + 1; else hi = m; }
        sHi = lo;
    }
    __syncthreads();
    int lo = sLo, hi = sHi;
    int l = t & 31, row = t >> 5;
    float acc = 0.0f;
    for (int i = lo + row; i < hi; i += 8)
        acc += H2[(size_t)i * D2 + l];
    sAcc[row * D2 + l] = acc;
    __syncthreads();
    if (row == 0) {
#pragma unroll
        for (int r = 1; r < 8; ++r) acc += sAcc[r * D2 + l];
        float c = (float)(hi - lo);
        out[g * D2 + l] = acc / fmaxf(c, 1.0f);
    }
}

extern "C" void kernel_launch(void* const* d_in, const int* in_sizes, int n_in,
                              void* d_out, int out_size, void* d_ws, size_t ws_size,
                              hipStream_t stream) {
    const void* feat = d_in[0];
    const void* W1 = d_in[1];  const void* al1 = d_in[2];  const void* ar1 = d_in[3];
    const void* res1 = d_in[4]; const void* b1 = d_in[5];
    const void* g1g = d_in[6]; const void* g1b = d_in[7];
    const void* g1m = d_in[8]; const void* g1v = d_in[9];
    const void* W2 = d_in[10]; const void* al2 = d_in[11]; const void* ar2 = d_in[12];
    const void* res2 = d_in[13]; const void* b2v = d_in[14];
    const void* g2g = d_in[15]; const void* g2b = d_in[16];
    const void* g2m = d_in[17]; const void* g2v = d_in[18];
    const void* Wd1 = d_in[19]; const void* bd1 = d_in[20];
    const void* gdg = d_in[21]; const void* gdb = d_in[22];
    const void* gdm = d_in[23]; const void* gdv = d_in[24];
    const void* Wd2 = d_in[25]; const void* bd2 = d_in[26];
    const int* src = (const int*)d_in[27];
    const int* dst = (const int*)d_in[28];
    const int* gid = (const int*)d_in[29];

    unsigned int* wsu = (unsigned int*)d_ws;
    int* deg    = (int*)(wsu + UO_DEG);
    int* cnt    = (int*)(wsu + UO_CNT);
    int* flag   = (int*)(wsu + UO_FLAG);
    int* loc    = (int*)(wsu + UO_LOC);
    int* bsum   = (int*)(wsu + UO_BSUM);
    int* carry  = (int*)(wsu + UO_CARRY);
    int* esrc   = (int*)(wsu + UO_ESRC);
    int* eoff   = (int*)(wsu + UO_EOFF);
    float* fcan = (float*)(wsu + UO_FCAN);
    float* cst  = (float*)(wsu + UO_CST);
    unsigned short* F2 = (unsigned short*)(wsu + UO_F2);
    float* RS2  = (float*)(wsu + UO_RS2);
    float* EL2  = (float*)(wsu + UO_EL2);
    float* ER2  = (float*)(wsu + UO_ER2);

    hipMemsetAsync(d_ws, 0, (size_t)ZERO_UNITS * 4, stream);

    k_prep<<<(NE + 255) / 256, 256, 0, stream>>>(feat, dst, fcan, deg, eoff,
                                                 W1, al1, ar1, res1, b1,
                                                 g1g, g1b, g1m, g1v,
                                                 b2v, g2g, g2b, g2m, g2v,
                                                 bd1, gdg, gdb, gdm, gdv,
                                                 flag, cst);
    k_scanA<<<NB, 256, 0, stream>>>(deg, loc, bsum, carry, cnt);
    k_fill<<<(NE + 255) / 256, 256, 0, stream>>>(src, dst, loc, carry, eoff, esrc);

    k_layer1<<<(NN + 31) / 32, 256, 0, stream>>>(fcan, W2, res2, al2, ar2, flag, cst,
                                                 loc, carry, esrc, F2, RS2, EL2, ER2);

    k_final<<<(NN * 32) / 256, 256, 0, stream>>>(Wd1, Wd2, bd2, flag, cst,
                                                 loc, carry, esrc, F2, RS2, EL2, ER2,
                                                 (float*)d_out);

    k_pool2<<<NG, 256, 0, stream>>>(gid, RS2, (float*)d_out);
}

// Round 16
// 291.381 us; speedup vs baseline: 1.1769x; 1.0068x over previous
//
#include <hip/hip_runtime.h>
#include <hip/hip_bf16.h>

#define NN 50000
#define NE 800000
#define NG 64
#define C1 128    // H1*D1
#define D2 32
#define NB 196    // (NN+255)/256 scan blocks
#define BN_EPS 1e-5f

// ---- constant-block layout (float offsets inside cst) ----
#define CST_A   0
#define CST_B   2
#define CST_P   4
#define CST_Q   132
#define CST_R   260
#define CST_SC2 388
#define CST_RC2 420
#define CST_SD  452
#define CST_RD  580
#define CST_N   1024

// ---- workspace layout (4-byte-unit offsets inside d_ws), total ~13.8 MiB ----
#define UO_DEG   0                        // int[NN]  (zeroed)
#define UO_CNT   50000                    // int[4]   (zeroed) scanA last-block counter
#define ZERO_UNITS 50004
#define UO_FLAG  50004                    // int[1]
#define UO_LOC   50008                    // int[NN]
#define UO_BSUM  100008                   // int[256]
#define UO_CARRY 100264                   // int[256]
#define UO_ESRC  100520                   // ushort[NE]  (node ids < 65536)
#define UO_EOFF  500520                   // ushort[NE]  slot-within-node
#define UO_FCAN  900520                   // float[NN]
#define UO_CST   950520                   // float[CST_N]
#define UO_F2    951544                   // ushort[D2*NN] bf16 (16B aligned)
#define UO_RS2   1751544                  // float[D2*NN]; overwritten with h2 by k_final
#define UO_EL2   3351544                  // float[NN]
#define UO_ER2   3401544                  // float[NN]
#define UO_END   3451544

__device__ __forceinline__ float lrelu(float x) { return x > 0.0f ? x : 0.2f * x; }
__device__ __forceinline__ float bu2f(unsigned int u) {
    union { unsigned int i; float f; } v; v.i = (u & 0xFFFFu) << 16; return v.f;
}
__device__ __forceinline__ unsigned short f2bu(float f) {
    union { float f; unsigned int i; } v; v.f = f;
    unsigned int r = v.i + 0x7FFFu + ((v.i >> 16) & 1u);
    return (unsigned short)(r >> 16);
}
__device__ __forceinline__ float pk_lo(unsigned int w) {
    union { unsigned int i; float f; } v; v.i = w << 16; return v.f;
}
__device__ __forceinline__ float pk_hi(unsigned int w) {
    union { unsigned int i; float f; } v; v.i = w & 0xFFFF0000u; return v.f;
}
__device__ __forceinline__ float ldw(const void* p, int i, int bf) {
    return bf ? bu2f(((const unsigned short*)p)[i]) : ((const float*)p)[i];
}
__device__ __forceinline__ int offat(const int* loc, const int* carry, int i) {
    return loc[i] + carry[i >> 8];
}
__device__ __forceinline__ int sniff64(const unsigned int* fw, int l) {
    int cnt = 0;
    for (int j = l; j < 256; j += 64) {
        unsigned int b = (fw[j] >> 8) & 0x7Fu;
        cnt += (b >= 0x3Au && b <= 0x41u) ? 1 : 0;
    }
#pragma unroll
    for (int m = 32; m >= 1; m >>= 1) cnt += __shfl_xor(cnt, m);
    return (cnt > 128) ? 1 : 0;
}

// ---------------- fcan convert + degree histogram (keeps slot) + (block 0) const folding ----------------
__global__ void k_prep(const void* __restrict__ feat, const int* __restrict__ dst,
                       float* __restrict__ fcan, int* __restrict__ deg,
                       unsigned short* __restrict__ eoff,
                       const void* W1, const void* al1, const void* ar1,
                       const void* res1, const void* b1,
                       const void* g1g, const void* g1b, const void* g1m, const void* g1v,
                       const void* b2v, const void* g2g, const void* g2b,
                       const void* g2m, const void* g2v,
                       const void* bd1, const void* gdg, const void* gdb,
                       const void* gdm, const void* gdv,
                       int* __restrict__ flag, float* __restrict__ cst) {
    __shared__ int sBf;
    int t = threadIdx.x;
    if (t < 64) {
        int bf = sniff64((const unsigned int*)feat, t);
        if (t == 0) sBf = bf;
    }
    __syncthreads();
    int bf = sBf;

    if (blockIdx.x == 0) {             // fold tiny weights into fp32 constants
        if (t == 0) *flag = bf;
        if (t < 128) {
            if (t < 2) {
                float a = 0.0f, b = 0.0f;
                for (int d = 0; d < 64; ++d) {
                    float w = ldw(W1, t * 64 + d, bf);
                    a += w * ldw(al1, t * 64 + d, bf);
                    b += w * ldw(ar1, t * 64 + d, bf);
                }
                cst[CST_A + t] = a;
                cst[CST_B + t] = b;
            }
            {
                float sc = rsqrtf(ldw(g1v, t, bf) + BN_EPS) * ldw(g1g, t, bf);
                cst[CST_P + t] = ldw(W1, t, bf) * sc;
                cst[CST_Q + t] = ldw(res1, t, bf) * sc;
                cst[CST_R + t] = (ldw(b1, t, bf) - ldw(g1m, t, bf)) * sc + ldw(g1b, t, bf);
            }
            if (t < D2) {
                float sc = rsqrtf(ldw(g2v, t, bf) + BN_EPS) * ldw(g2g, t, bf);
                cst[CST_SC2 + t] = sc;
                cst[CST_RC2 + t] = (ldw(b2v, t, bf) - ldw(g2m, t, bf)) * sc + ldw(g2b, t, bf);
            }
            {
                float sc = rsqrtf(ldw(gdv, t, bf) + BN_EPS) * ldw(gdg, t, bf);
                cst[CST_SD + t] = sc;
                cst[CST_RD + t] = (ldw(bd1, t, bf) - ldw(gdm, t, bf)) * sc + ldw(gdb, t, bf);
            }
        }
    }

    int k = blockIdx.x * blockDim.x + t;
    if (k < NN) fcan[k] = ldw(feat, k, bf);
    if (k < NE) eoff[k] = (unsigned short)atomicAdd(&deg[dst[k]], 1);
}

// ---------------- scan: per-block exclusive scan + last-block does the carry scan ----------------
__global__ __launch_bounds__(256) void k_scanA(const int* __restrict__ deg,
                                               int* __restrict__ loc,
                                               int* __restrict__ bsum,
                                               int* __restrict__ carry,
                                               int* __restrict__ cnt) {
    __shared__ int tmp[256];
    __shared__ int isLast;
    int t = threadIdx.x;
    int i = blockIdx.x * 256 + t;
    int v = (i < NN) ? deg[i] : 0;
    tmp[t] = v;
    __syncthreads();
    for (int off = 1; off < 256; off <<= 1) {
        int u = (t >= off) ? tmp[t - off] : 0;
        __syncthreads();
        tmp[t] += u;
        __syncthreads();
    }
    if (i < NN) loc[i] = tmp[t] - v;
    if (t == 255) {
        bsum[blockIdx.x] = tmp[255];
        __threadfence();
        int old = atomicAdd(cnt, 1);
        isLast = (old == NB - 1) ? 1 : 0;
    }
    __syncthreads();
    if (isLast) {
        __threadfence();
        int bv = (t < NB) ? bsum[t] : 0;
        tmp[t] = bv;
        __syncthreads();
        for (int off = 1; off < 256; off <<= 1) {
            int u = (t >= off) ? tmp[t - off] : 0;
            __syncthreads();
            tmp[t] += u;
            __syncthreads();
        }
        carry[t] = tmp[t] - bv;
    }
}

// ---------------- CSR fill: atomic-free, ushort payload (halved scatter amplification) ----------------
__global__ void k_fill(const int* __restrict__ src, const int* __restrict__ dst,
                       const int* __restrict__ loc, const int* __restrict__ carry,
                       const unsigned short* __restrict__ eoff,
                       unsigned short* __restrict__ esrc) {
    int k = blockIdx.x * blockDim.x + threadIdx.x;
    if (k >= NE) return;
    int d = dst[k];
    esrc[offat(loc, carry, d) + (int)eoff[k]] = (unsigned short)src[k];
}

// ---------------- layer-1: 32 nodes/block; interleaved phase-1 chains + packed projection ----------------
__global__ __launch_bounds__(256) void k_layer1(
        const float* __restrict__ fcan, const void* W2, const void* res2,
        const void* al2, const void* ar2,
        const int* __restrict__ flag, const float* __restrict__ cst,
        const int* __restrict__ loc, const int* __restrict__ carry,
        const unsigned short* __restrict__ esrc,
        unsigned short* __restrict__ F2, float* __restrict__ RS2,
        float* __restrict__ EL2, float* __restrict__ ER2) {
    __shared__ unsigned int sW2pk[32 * 66];  // [l][cw], (c,c+64) bf16 pairs
    __shared__ unsigned int sR2pk[32 * 66];
    __shared__ unsigned int sH1pk[32 * 66];
    __shared__ float sP[C1], sQ[C1], sR[C1];
    __shared__ float sAl[D2], sAr[D2];
    int t = threadIdx.x;
    int bf = *flag;
    for (int u = t; u < 2048; u += 256) {
        int cw = u >> 5, l2 = u & 31;
        unsigned int wlo = (unsigned int)f2bu(ldw(W2, cw * D2 + l2, bf));
        unsigned int whi = (unsigned int)f2bu(ldw(W2, (cw + 64) * D2 + l2, bf));
        sW2pk[l2 * 66 + cw] = wlo | (whi << 16);
        unsigned int rlo = (unsigned int)f2bu(ldw(res2, cw * D2 + l2, bf));
        unsigned int rhi = (unsigned int)f2bu(ldw(res2, (cw + 64) * D2 + l2, bf));
        sR2pk[l2 * 66 + cw] = rlo | (rhi << 16);
    }
    if (t < C1) { sP[t] = cst[CST_P + t]; sQ[t] = cst[CST_Q + t]; sR[t] = cst[CST_R + t]; }
    if (t < D2) { sAl[t] = ldw(al2, t, bf); sAr[t] = ldw(ar2, t, bf); }
    __syncthreads();

    int l = t & 31;
    int g = t >> 5;
    int base = blockIdx.x * 32;
    float A0 = cst[CST_A + 0], A1 = cst[CST_A + 1];
    float B0 = cst[CST_B + 0], B1 = cst[CST_B + 1];

    int e0k[4], e1k[4];
    float fiK[4];
#pragma unroll
    for (int k = 0; k < 4; ++k) {
        int i = base + g * 4 + k;
        if (i < NN) {
            e0k[k] = offat(loc, carry, i);
            e1k[k] = (i + 1 < NN) ? offat(loc, carry, i + 1) : NE;
            fiK[k] = fcan[i];
        } else { e0k[k] = 0; e1k[k] = 0; fiK[k] = 0.0f; }
    }
    float S0[4], S1[4], N0[4], N1[4];
#pragma unroll
    for (int k = 0; k < 4; ++k) { S0[k] = S1[k] = N0[k] = N1[k] = 0.0f; }
    int sA[4];
#pragma unroll
    for (int k = 0; k < 4; ++k) sA[k] = (e0k[k] + l < e1k[k]) ? (int)esrc[e0k[k] + l] : 0;
    float fA[4];
#pragma unroll
    for (int k = 0; k < 4; ++k) fA[k] = fcan[sA[k]];
#pragma unroll
    for (int k = 0; k < 4; ++k) {
        if (e0k[k] + l < e1k[k]) {
            float w0 = __expf(lrelu(A0 * fA[k] + B0 * fiK[k]));
            float w1 = __expf(lrelu(A1 * fA[k] + B1 * fiK[k]));
            S0[k] += w0; N0[k] += w0 * fA[k];
            S1[k] += w1; N1[k] += w1 * fA[k];
        }
    }
#pragma unroll
    for (int k = 0; k < 4; ++k) {
        for (int e = e0k[k] + l + 32; e < e1k[k]; e += 32) {
            int s = (int)esrc[e];
            float fs = fcan[s];
            float w0 = __expf(lrelu(A0 * fs + B0 * fiK[k]));
            float w1 = __expf(lrelu(A1 * fs + B1 * fiK[k]));
            S0[k] += w0; N0[k] += w0 * fs;
            S1[k] += w1; N1[k] += w1 * fs;
        }
    }
#pragma unroll
    for (int m = 16; m >= 1; m >>= 1) {
#pragma unroll
        for (int k = 0; k < 4; ++k) {
            S0[k] += __shfl_xor(S0[k], m); N0[k] += __shfl_xor(N0[k], m);
            S1[k] += __shfl_xor(S1[k], m); N1[k] += __shfl_xor(N1[k], m);
        }
    }
#pragma unroll
    for (int k = 0; k < 4; ++k) {
        int slot = g * 4 + k;
        float T0 = S0[k] > 0.0f ? N0[k] / S0[k] : 0.0f;
        float T1 = S1[k] > 0.0f ? N1[k] / S1[k] : 0.0f;
        float h0  = fmaxf(sP[l]      * T0 + sQ[l]      * fiK[k] + sR[l],      0.0f);
        float h1v = fmaxf(sP[l + 32] * T0 + sQ[l + 32] * fiK[k] + sR[l + 32], 0.0f);
        float h2v = fmaxf(sP[l + 64] * T1 + sQ[l + 64] * fiK[k] + sR[l + 64], 0.0f);
        float h3v = fmaxf(sP[l + 96] * T1 + sQ[l + 96] * fiK[k] + sR[l + 96], 0.0f);
        sH1pk[slot * 66 + l]      = (unsigned int)f2bu(h0)  | ((unsigned int)f2bu(h2v) << 16);
        sH1pk[slot * 66 + l + 32] = (unsigned int)f2bu(h1v) | ((unsigned int)f2bu(h3v) << 16);
    }
    __syncthreads();

    int w = t >> 6;
    int half = (t >> 5) & 1;
    int nb0 = w * 8 + half * 4;
    float aF[4] = {0.f, 0.f, 0.f, 0.f}, aR[4] = {0.f, 0.f, 0.f, 0.f};
    for (int cw = 0; cw < 64; cw += 2) {
        uint2 wq = *(const uint2*)&sW2pk[l * 66 + cw];
        uint2 rq = *(const uint2*)&sR2pk[l * 66 + cw];
        float w_a = pk_lo(wq.x), w_b = pk_hi(wq.x), w_c = pk_lo(wq.y), w_d = pk_hi(wq.y);
        float r_a = pk_lo(rq.x), r_b = pk_hi(rq.x), r_c = pk_lo(rq.y), r_d = pk_hi(rq.y);
#pragma unroll
        for (int n = 0; n < 4; ++n) {
            uint2 hq = *(const uint2*)&sH1pk[(nb0 + n) * 66 + cw];
            float h_a = pk_lo(hq.x), h_b = pk_hi(hq.x), h_c = pk_lo(hq.y), h_d = pk_hi(hq.y);
            aF[n] = fmaf(h_a, w_a, fmaf(h_b, w_b, fmaf(h_c, w_c, fmaf(h_d, w_d, aF[n]))));
            aR[n] = fmaf(h_a, r_a, fmaf(h_b, r_b, fmaf(h_c, r_c, fmaf(h_d, r_d, aR[n]))));
        }
    }
#pragma unroll
    for (int n = 0; n < 4; ++n) {
        int i = base + nb0 + n;
        if (i < NN) {
            float elp = aF[n] * sAl[l], erp = aF[n] * sAr[l];
#pragma unroll
            for (int m = 16; m >= 1; m >>= 1) {
                elp += __shfl_xor(elp, m);
                erp += __shfl_xor(erp, m);
            }
            if (l == 0) { EL2[i] = elp; ER2[i] = erp; }
            F2[(size_t)i * D2 + l]  = f2bu(aF[n]);
            RS2[(size_t)i * D2 + l] = aR[n];
        }
    }
}

// ---------------- layer-2 gather (4-way unrolled chains) + BN2/ReLU + decoder ----------------
__global__ __launch_bounds__(256) void k_final(
        const void* Wd1, const void* Wd2, const void* bd2,
        const int* __restrict__ flag, const float* __restrict__ cst,
        const int* __restrict__ loc, const int* __restrict__ carry,
        const unsigned short* __restrict__ esrc,
        const unsigned short* __restrict__ F2, float* __restrict__ RS2,
        const float* __restrict__ EL2, const float* __restrict__ ER2,
        float* __restrict__ out) {
    __shared__ float sWd1[C1 * D2];
    __shared__ float sWd2[C1];
    __shared__ float sSd[C1], sRd[C1];
    __shared__ float sSc2[D2], sRc2[D2];
    __shared__ float sH2[8 * D2];
    int t = threadIdx.x;
    int bf = *flag;
    for (int u = t; u < C1 * D2; u += 256) sWd1[u] = ldw(Wd1, u, bf);
    for (int u = t; u < C1; u += 256) {
        sWd2[u] = ldw(Wd2, u, bf);
        sSd[u] = cst[CST_SD + u]; sRd[u] = cst[CST_RD + u];
    }
    if (t < D2) { sSc2[t] = cst[CST_SC2 + t]; sRc2[t] = cst[CST_RC2 + t]; }
    __syncthreads();

    int i = (blockIdx.x * 256 + t) >> 5;
    int l = t & 31;
    int nb = t >> 5;

    float eri = ER2[i];
    int e0 = offat(loc, carry, i);
    int e1 = (i + 1 < NN) ? offat(loc, carry, i + 1) : NE;
    float aF0 = 0.0f, aF1 = 0.0f, aF2 = 0.0f, aF3 = 0.0f;
    float S0 = 0.0f, S1 = 0.0f, S2 = 0.0f, S3 = 0.0f;
    int e = e0;
    for (; e + 3 < e1; e += 4) {
        int sA = (int)esrc[e];
        int sB = (int)esrc[e + 1];
        int sC = (int)esrc[e + 2];
        int sD = (int)esrc[e + 3];
        float wA = __expf(lrelu(EL2[sA] + eri));
        float wB = __expf(lrelu(EL2[sB] + eri));
        float wC = __expf(lrelu(EL2[sC] + eri));
        float wD = __expf(lrelu(EL2[sD] + eri));
        float vA = bu2f(F2[(size_t)sA * D2 + l]);
        float vB = bu2f(F2[(size_t)sB * D2 + l]);
        float vC = bu2f(F2[(size_t)sC * D2 + l]);
        float vD = bu2f(F2[(size_t)sD * D2 + l]);
        S0 += wA; S1 += wB; S2 += wC; S3 += wD;
        aF0 = fmaf(wA, vA, aF0);
        aF1 = fmaf(wB, vB, aF1);
        aF2 = fmaf(wC, vC, aF2);
        aF3 = fmaf(wD, vD, aF3);
    }
    for (; e < e1; ++e) {
        int sA = (int)esrc[e];
        float wA = __expf(lrelu(EL2[sA] + eri));
        S0 += wA;
        aF0 = fmaf(wA, bu2f(F2[(size_t)sA * D2 + l]), aF0);
    }
    float S = (S0 + S1) + (S2 + S3);
    float aF = (aF0 + aF1) + (aF2 + aF3);
    float inv = S > 0.0f ? 1.0f / S : 0.0f;

    float h2 = fmaxf((aF * inv + RS2[(size_t)i * D2 + l]) * sSc2[l] + sRc2[l], 0.0f);
    RS2[(size_t)i * D2 + l] = h2;

    sH2[nb * D2 + l] = h2;
    float rec = 0.0f;
#pragma unroll
    for (int jj = 0; jj < 4; ++jj) {
        int j = l + jj * 32;
        float acc = 0.0f;
#pragma unroll
        for (int d = 0; d < D2; ++d)
            acc = fmaf(sH2[nb * D2 + d], sWd1[d * C1 + j], acc);
        float dj = fmaxf(acc * sSd[j] + sRd[j], 0.0f);
        rec = fmaf(dj, sWd2[j], rec);
    }
#pragma unroll
    for (int m = 16; m >= 1; m >>= 1) rec += __shfl_xor(rec, m);
    if (l == 0) out[NG * D2 + i] = rec + ldw(bd2, 0, bf);
}

// ---------------- graph mean pool: one block per graph, zero atomics ----------------
__global__ __launch_bounds__(256) void k_pool2(const int* __restrict__ gid,
                                               const float* __restrict__ H2,
                                               float* __restrict__ out) {
    __shared__ int sLo, sHi;
    __shared__ float sAcc[8 * D2];
    int g = blockIdx.x;
    int t = threadIdx.x;
    if (t == 0) {
        int lo = 0, hi = NN;
        while (lo < hi) { int m = (lo + hi) >> 1; if (gid[m] < g) lo = m + 1; else hi = m; }
        sLo = lo;
        lo = 0; hi = NN;
        while (lo < hi) { int m = (lo + hi) >> 1; if (gid[m] < g + 1) lo = m + 1; else hi = m; }
        sHi = lo;
    }
    __syncthreads();
    int lo = sLo, hi = sHi;
    int l = t & 31, row = t >> 5;
    float acc = 0.0f;
    for (int i = lo + row; i < hi; i += 8)
        acc += H2[(size_t)i * D2 + l];
    sAcc[row * D2 + l] = acc;
    __syncthreads();
    if (row == 0) {
#pragma unroll
        for (int r = 1; r < 8; ++r) acc += sAcc[r * D2 + l];
        float c = (float)(hi - lo);
        out[g * D2 + l] = acc / fmaxf(c, 1.0f);
    }
}

extern "C" void kernel_launch(void* const* d_in, const int* in_sizes, int n_in,
                              void* d_out, int out_size, void* d_ws, size_t ws_size,
                              hipStream_t stream) {
    const void* feat = d_in[0];
    const void* W1 = d_in[1];  const void* al1 = d_in[2];  const void* ar1 = d_in[3];
    const void* res1 = d_in[4]; const void* b1 = d_in[5];
    const void* g1g = d_in[6]; const void* g1b = d_in[7];
    const void* g1m = d_in[8]; const void* g1v = d_in[9];
    const void* W2 = d_in[10]; const void* al2 = d_in[11]; const void* ar2 = d_in[12];
    const void* res2 = d_in[13]; const void* b2v = d_in[14];
    const void* g2g = d_in[15]; const void* g2b = d_in[16];
    const void* g2m = d_in[17]; const void* g2v = d_in[18];
    const void* Wd1 = d_in[19]; const void* bd1 = d_in[20];
    const void* gdg = d_in[21]; const void* gdb = d_in[22];
    const void* gdm = d_in[23]; const void* gdv = d_in[24];
    const void* Wd2 = d_in[25]; const void* bd2 = d_in[26];
    const int* src = (const int*)d_in[27];
    const int* dst = (const int*)d_in[28];
    const int* gid = (const int*)d_in[29];

    unsigned int* wsu = (unsigned int*)d_ws;
    int* deg    = (int*)(wsu + UO_DEG);
    int* cnt    = (int*)(wsu + UO_CNT);
    int* flag   = (int*)(wsu + UO_FLAG);
    int* loc    = (int*)(wsu + UO_LOC);
    int* bsum   = (int*)(wsu + UO_BSUM);
    int* carry  = (int*)(wsu + UO_CARRY);
    unsigned short* esrc = (unsigned short*)(wsu + UO_ESRC);
    unsigned short* eoff = (unsigned short*)(wsu + UO_EOFF);
    float* fcan = (float*)(wsu + UO_FCAN);
    float* cst  = (float*)(wsu + UO_CST);
    unsigned short* F2 = (unsigned short*)(wsu + UO_F2);
    float* RS2  = (float*)(wsu + UO_RS2);
    float* EL2  = (float*)(wsu + UO_EL2);
    float* ER2  = (float*)(wsu + UO_ER2);

    hipMemsetAsync(d_ws, 0, (size_t)ZERO_UNITS * 4, stream);

    k_prep<<<(NE + 255) / 256, 256, 0, stream>>>(feat, dst, fcan, deg, eoff,
                                                 W1, al1, ar1, res1, b1,
                                                 g1g, g1b, g1m, g1v,
                                                 b2v, g2g, g2b, g2m, g2v,
                                                 bd1, gdg, gdb, gdm, gdv,
                                                 flag, cst);
    k_scanA<<<NB, 256, 0, stream>>>(deg, loc, bsum, carry, cnt);
    k_fill<<<(NE + 255) / 256, 256, 0, stream>>>(src, dst, loc, carry, eoff, esrc);

    k_layer1<<<(NN + 31) / 32, 256, 0, stream>>>(fcan, W2, res2, al2, ar2, flag, cst,
                                                 loc, carry, esrc, F2, RS2, EL2, ER2);

    k_final<<<(NN * 32) / 256, 256, 0, stream>>>(Wd1, Wd2, bd2, flag, cst,
                                                 loc, carry, esrc, F2, RS2, EL2, ER2,
                                                 (float*)d_out);

    k_pool2<<<NG, 256, 0, stream>>>(gid, RS2, (float*)d_out);
}